// Round 2
// baseline (26.185 us; speedup 1.0000x reference)
//
#include <hip/hip_runtime.h>
#include <hip/hip_bf16.h>

namespace {

constexpr int NO = 256;
constexpr int NK = 32;
constexpr int NI = 512;

__device__ __forceinline__ float bf2f(const __hip_bfloat16 x) { return __bfloat162float(x); }

// Detect whether a buffer that *should* contain weights in [0.1, 1.1] is
// stored as bf16 or f32. Reading a little-endian f32 buffer as bf16 puts the
// low mantissa half-word at EVEN bf16 indices -> random bit patterns. If all
// 16 even elements decode into the plausible weight range, it's bf16.
__device__ __forceinline__ bool detect_bf16(const void* wptr) {
  const __hip_bfloat16* h = (const __hip_bfloat16*)wptr;
  int ok = 0;
  #pragma unroll
  for (int e = 0; e < 32; e += 2) {
    const float v = bf2f(h[e]);
    ok += (v >= 0.05f && v <= 1.2f) ? 1 : 0;
  }
  return ok == 16;
}

__device__ __forceinline__ float ldf(const void* p, int i, bool bf) {
  return bf ? bf2f(((const __hip_bfloat16*)p)[i]) : ((const float*)p)[i];
}

__device__ __forceinline__ void stf(void* p, int i, float v, bool bf) {
  if (bf) ((__hip_bfloat16*)p)[i] = __float2bfloat16(v);
  else    ((float*)p)[i]          = v;
}

// ws layout (floats): [0]=S, [1..3]=mbar, [4..12]=Cbar(3x3), [13]=bf16 flag,
//                     [16 + 3*r ..] = anchor[r], r=0..255
__global__ __launch_bounds__(NI) void gm_reduce_kernel(
    const void* __restrict__ weights,   // (512)
    const void* __restrict__ means,     // (512,3)
    const void* __restrict__ covars,    // (512,3,3)
    float* __restrict__ ws)
{
  __shared__ float sw[NI];
  __shared__ float red[8][8];
  __shared__ float s_stat[4];

  const int i    = threadIdx.x;      // 0..511
  const int lane = i & 63;
  const int wave = i >> 6;

  const bool bf = detect_bf16(weights);

  const float w  = ldf(weights, i, bf);
  const float m0 = ldf(means, 3 * i + 0, bf);
  const float m1 = ldf(means, 3 * i + 1, bf);
  const float m2 = ldf(means, 3 * i + 2, bf);
  sw[i] = w;

  // ---- pass 1: S and sum(w*m) ----
  float v0 = w, v1 = w * m0, v2 = w * m1, v3 = w * m2;
  #pragma unroll
  for (int off = 32; off > 0; off >>= 1) {
    v0 += __shfl_down(v0, off, 64);
    v1 += __shfl_down(v1, off, 64);
    v2 += __shfl_down(v2, off, 64);
    v3 += __shfl_down(v3, off, 64);
  }
  if (lane == 0) { red[wave][0] = v0; red[wave][1] = v1; red[wave][2] = v2; red[wave][3] = v3; }
  __syncthreads();
  if (i == 0) {
    float S = 0.f, M0 = 0.f, M1 = 0.f, M2 = 0.f;
    for (int t = 0; t < 8; ++t) { S += red[t][0]; M0 += red[t][1]; M1 += red[t][2]; M2 += red[t][3]; }
    s_stat[0] = S; s_stat[1] = M0 / S; s_stat[2] = M1 / S; s_stat[3] = M2 / S;
  }
  __syncthreads();
  const float S  = s_stat[0];
  const float b0 = s_stat[1], b1 = s_stat[2], b2 = s_stat[3];
  const float d0 = m0 - b0, d1 = m1 - b1, d2 = m2 - b2;

  // ---- pass 2: sum w*(covar_i + d d^T), 6 symmetric entries ----
  const float c00 = ldf(covars, 9 * i + 0, bf);
  const float c01 = ldf(covars, 9 * i + 1, bf);
  const float c02 = ldf(covars, 9 * i + 2, bf);
  const float c11 = ldf(covars, 9 * i + 4, bf);
  const float c12 = ldf(covars, 9 * i + 5, bf);
  const float c22 = ldf(covars, 9 * i + 8, bf);
  float u0 = w * (c00 + d0 * d0);
  float u1 = w * (c01 + d0 * d1);
  float u2 = w * (c02 + d0 * d2);
  float u3 = w * (c11 + d1 * d1);
  float u4 = w * (c12 + d1 * d2);
  float u5 = w * (c22 + d2 * d2);
  __syncthreads();   // red[] reuse safe after this
  #pragma unroll
  for (int off = 32; off > 0; off >>= 1) {
    u0 += __shfl_down(u0, off, 64);
    u1 += __shfl_down(u1, off, 64);
    u2 += __shfl_down(u2, off, 64);
    u3 += __shfl_down(u3, off, 64);
    u4 += __shfl_down(u4, off, 64);
    u5 += __shfl_down(u5, off, 64);
  }
  if (lane == 0) {
    red[wave][0] = u0; red[wave][1] = u1; red[wave][2] = u2;
    red[wave][3] = u3; red[wave][4] = u4; red[wave][5] = u5;
  }
  __syncthreads();
  if (i == 0) {
    float t0 = 0.f, t1 = 0.f, t2 = 0.f, t3 = 0.f, t4 = 0.f, t5 = 0.f;
    for (int t = 0; t < 8; ++t) {
      t0 += red[t][0]; t1 += red[t][1]; t2 += red[t][2];
      t3 += red[t][3]; t4 += red[t][4]; t5 += red[t][5];
    }
    ws[0] = S; ws[1] = b0; ws[2] = b1; ws[3] = b2;
    const float C00 = t0 / S, C01 = t1 / S, C02 = t2 / S;
    const float C11 = t3 / S, C12 = t4 / S, C22 = t5 / S;
    ws[4]  = C00; ws[5]  = C01; ws[6]  = C02;
    ws[7]  = C01; ws[8]  = C11; ws[9]  = C12;
    ws[10] = C02; ws[11] = C12; ws[12] = C22;
    ws[13] = bf ? 1.0f : 0.0f;
  }

  // ---- top-k (No=256), jax.lax.top_k tie semantics (stable desc sort) ----
  const float wi = sw[i];
  int rank = 0;
  for (int j = 0; j < NI; ++j) {
    const float wj = sw[j];
    rank += (int)((wj > wi) || (wj == wi && j < i));
  }
  if (rank < NO) {
    ws[16 + 3 * rank + 0] = m0;
    ws[16 + 3 * rank + 1] = m1;
    ws[16 + 3 * rank + 2] = m2;
  }
}

__global__ __launch_bounds__(256) void gm_emit_kernel(
    const void* __restrict__ k_weights, // (256,32)
    const void* __restrict__ k_means,   // (256,32,3)
    const void* __restrict__ k_scales,  // (256,32,3)
    const void* __restrict__ k_quats,   // (256,32,4)
    const float* __restrict__ ws,
    void* __restrict__ out)             // [W 8192][mu 24576][cov 73728]
{
  const int t = blockIdx.x * 256 + threadIdx.x;   // 0..8191 == o*32+k
  if (t >= NO * NK) return;
  const int o = t >> 5;

  const bool bf = (ws[13] != 0.0f);

  const float S  = ws[0];
  const float b0 = ws[1], b1 = ws[2], b2 = ws[3];
  float Cb[9];
  #pragma unroll
  for (int e = 0; e < 9; ++e) Cb[e] = ws[4 + e];
  const float a0 = ws[16 + 3 * o + 0];
  const float a1 = ws[16 + 3 * o + 1];
  const float a2 = ws[16 + 3 * o + 2];

  const float kw  = ldf(k_weights, t, bf);
  const float km0 = ldf(k_means, 3 * t + 0, bf);
  const float km1 = ldf(k_means, 3 * t + 1, bf);
  const float km2 = ldf(k_means, 3 * t + 2, bf);
  float qw = ldf(k_quats, 4 * t + 0, bf);
  float qx = ldf(k_quats, 4 * t + 1, bf);
  float qy = ldf(k_quats, 4 * t + 2, bf);
  float qz = ldf(k_quats, 4 * t + 3, bf);
  const float s0 = ldf(k_scales, 3 * t + 0, bf);
  const float s1 = ldf(k_scales, 3 * t + 1, bf);
  const float s2 = ldf(k_scales, 3 * t + 2, bf);

  const float rn = rsqrtf(qw * qw + qx * qx + qy * qy + qz * qz);
  qw *= rn; qx *= rn; qy *= rn; qz *= rn;

  float R[3][3];
  R[0][0] = 1.f - 2.f * (qy * qy + qz * qz);
  R[0][1] = 2.f * (qx * qy - qw * qz);
  R[0][2] = 2.f * (qx * qz + qw * qy);
  R[1][0] = 2.f * (qx * qy + qw * qz);
  R[1][1] = 1.f - 2.f * (qx * qx + qz * qz);
  R[1][2] = 2.f * (qy * qz - qw * qx);
  R[2][0] = 2.f * (qx * qz - qw * qy);
  R[2][1] = 2.f * (qy * qz + qw * qx);
  R[2][2] = 1.f - 2.f * (qx * qx + qy * qy);

  const float sc[3] = { s0, s1, s2 };
  float M[3][3];
  #pragma unroll
  for (int r = 0; r < 3; ++r)
    #pragma unroll
    for (int c = 0; c < 3; ++c)
      M[r][c] = R[r][c] * sc[c];

  // cov = M M^T + Cbar
  float cov[9];
  #pragma unroll
  for (int r = 0; r < 3; ++r) {
    #pragma unroll
    for (int c = 0; c < 3; ++c) {
      float acc = Cb[3 * r + c];
      #pragma unroll
      for (int e = 0; e < 3; ++e) acc += M[r][e] * M[c][e];
      cov[3 * r + c] = acc;
    }
  }

  // ---- outputs ----
  stf(out, t, kw * S, bf);

  const int mu_base = NO * NK + 3 * t;
  stf(out, mu_base + 0, a0 + km0 + b0, bf);
  stf(out, mu_base + 1, a1 + km1 + b1, bf);
  stf(out, mu_base + 2, a2 + km2 + b2, bf);

  const int cov_base = NO * NK * 4 + 9 * t;
  #pragma unroll
  for (int e = 0; e < 9; ++e)
    stf(out, cov_base + e, cov[e], bf);
}

} // anonymous namespace

extern "C" void kernel_launch(void* const* d_in, const int* in_sizes, int n_in,
                              void* d_out, int out_size, void* d_ws, size_t ws_size,
                              hipStream_t stream) {
  const void* weights   = d_in[0];
  const void* means     = d_in[1];
  const void* covars    = d_in[2];
  // d_in[3] = features — unused by the reference
  const void* k_weights = d_in[4];
  const void* k_means   = d_in[5];
  const void* k_scales  = d_in[6];
  const void* k_quats   = d_in[7];

  float* ws = (float*)d_ws;

  gm_reduce_kernel<<<1, NI, 0, stream>>>(weights, means, covars, ws);
  gm_emit_kernel<<<(NO * NK) / 256, 256, 0, stream>>>(k_weights, k_means, k_scales, k_quats, ws, d_out);
}